// Round 1
// baseline (682.661 us; speedup 1.0000x reference)
//
#include <hip/hip_runtime.h>

// ---------- types ----------
typedef unsigned short u16;
typedef __bf16  bf16x8 __attribute__((ext_vector_type(8)));
typedef short   short8 __attribute__((ext_vector_type(8)));
typedef float   f32x4  __attribute__((ext_vector_type(4)));
typedef u16     u16x4  __attribute__((ext_vector_type(4)));

__device__ __forceinline__ u16 f2bf(float f) {
  unsigned b = __builtin_bit_cast(unsigned, f);
  b += 0x7fffu + ((b >> 16) & 1u);          // round-to-nearest-even
  return (u16)(b >> 16);
}
__device__ __forceinline__ float bf2f(u16 u) {
  return __builtin_bit_cast(float, (unsigned)u << 16);
}
__device__ __forceinline__ f32x4 mfma16(short8 a, short8 b, f32x4 c) {
  return __builtin_amdgcn_mfma_f32_16x16x32_bf16(
      __builtin_bit_cast(bf16x8, a), __builtin_bit_cast(bf16x8, b), c, 0, 0, 0);
}
__device__ __forceinline__ void gload_lds16(const void* g, void* l) {
  __builtin_amdgcn_global_load_lds(
      (const __attribute__((address_space(1))) void*)g,
      (__attribute__((address_space(3))) void*)l, 16, 0, 0);
}

// ---------- cast x -> bf16 ----------
__global__ __launch_bounds__(256) void castk(const float* __restrict__ in,
                                             u16* __restrict__ out, int n4) {
  int i = blockIdx.x * 256 + threadIdx.x;
  if (i >= n4) return;
  float4 v = ((const float4*)in)[i];
  u16x4 o;
  o[0] = f2bf(v.x); o[1] = f2bf(v.y); o[2] = f2bf(v.z); o[3] = f2bf(v.w);
  *(u16x4*)&out[i * 4] = o;
}

// ---------- transpose-cast weight: W[K][N] f32 -> Wt[N][K] bf16 ----------
__global__ __launch_bounds__(256) void tcast(const float* __restrict__ W,
                                             u16* __restrict__ Wt, int K, int N) {
  __shared__ float tile[64][65];
  const int k0 = blockIdx.x * 64, n0 = blockIdx.y * 64;
  const int tc = threadIdx.x & 63, tr = threadIdx.x >> 6;
#pragma unroll
  for (int r = tr; r < 64; r += 4)
    tile[r][tc] = W[(size_t)(k0 + r) * N + n0 + tc];
  __syncthreads();
#pragma unroll
  for (int r = tr; r < 64; r += 4)
    Wt[(size_t)(n0 + r) * K + k0 + tc] = f2bf(tile[tc][r]);
}

// ---------- GEMM: C[M][N] = A[M][K] * Bt[N][K]^T  (bf16 in, fp32 acc) ----------
// 128x128 tile, BK=32, 256 threads (4 waves, each 64x64 = 4x4 frags of 16x16)
// EPI: 0 = bf16 store, 1 = bf16 store with nope col remap (c -> (c>>7)*192 + (c&127)),
//      2 = fp32 store
template <int EPI>
__global__ __launch_bounds__(256) void gemm_bt(const u16* __restrict__ A, int lda,
                                               const u16* __restrict__ Bt, int ldb,
                                               void* __restrict__ Cout, int ldc,
                                               int K) {
  __shared__ u16 As[128 * 32];
  __shared__ u16 Bs[128 * 32];
  const int t = threadIdx.x, w = t >> 6, l = t & 63;
  const int lr = l & 15, lk8 = (l >> 4) * 8, lg4 = (l >> 4) * 4;
  const int m0 = blockIdx.x * 128, n0 = blockIdx.y * 128;
  const int wr = (w >> 1) * 64, wc = (w & 1) * 64;

  f32x4 acc[4][4] = {};

  for (int k0 = 0; k0 < K; k0 += 32) {
#pragma unroll
    for (int i = 0; i < 2; ++i) {
      int lb = i * 4096 + t * 16;     // linear byte in 8KB tile
      int row = lb >> 6;              // 64B per row (32 bf16)
      int col = (lb & 63) >> 1;       // element col
      gload_lds16(A + (size_t)(m0 + row) * lda + k0 + col,
                  (char*)As + i * 4096 + w * 1024);
      gload_lds16(Bt + (size_t)(n0 + row) * ldb + k0 + col,
                  (char*)Bs + i * 4096 + w * 1024);
    }
    __syncthreads();
    short8 af[4], bf[4];
#pragma unroll
    for (int m = 0; m < 4; ++m)
      af[m] = *(const short8*)&As[(wr + m * 16 + lr) * 32 + lk8];
#pragma unroll
    for (int n = 0; n < 4; ++n)
      bf[n] = *(const short8*)&Bs[(wc + n * 16 + lr) * 32 + lk8];
#pragma unroll
    for (int m = 0; m < 4; ++m)
#pragma unroll
      for (int n = 0; n < 4; ++n)
        acc[m][n] = mfma16(af[m], bf[n], acc[m][n]);
    __syncthreads();
  }

#pragma unroll
  for (int m = 0; m < 4; ++m)
#pragma unroll
    for (int n = 0; n < 4; ++n)
#pragma unroll
      for (int j = 0; j < 4; ++j) {
        int r = m0 + wr + m * 16 + lg4 + j;
        int c = n0 + wc + n * 16 + lr;
        float v = acc[m][n][j];
        if (EPI == 0) {
          ((u16*)Cout)[(size_t)r * ldc + c] = f2bf(v);
        } else if (EPI == 1) {
          int cc = (c >> 7) * 192 + (c & 127);
          ((u16*)Cout)[(size_t)r * ldc + cc] = f2bf(v);
        } else {
          ((float*)Cout)[(size_t)r * ldc + c] = v;
        }
      }
}

// ---------- RoPE: src[4096][1024] (h*64 + 2i interleaved) -> dst cols h*192+128+2i ----------
__global__ __launch_bounds__(256) void rope_k(const u16* __restrict__ src,
                                              u16* __restrict__ dst) {
  int idx = blockIdx.x * 256 + threadIdx.x;   // 4096*16*32 = 2M pairs
  int row = idx >> 9;
  int rem = idx & 511;
  int h = rem >> 5, i = rem & 31;
  int tpos = row & 1023;
  float inv = powf(10000.0f, -(float)i * (1.0f / 32.0f));
  float f = (float)tpos * inv;
  float s, c;
  sincosf(f, &s, &c);
  float x1 = bf2f(src[(size_t)row * 1024 + h * 64 + 2 * i]);
  float x2 = bf2f(src[(size_t)row * 1024 + h * 64 + 2 * i + 1]);
  size_t o = (size_t)row * 3072 + h * 192 + 128 + 2 * i;
  dst[o]     = f2bf(x1 * c - x2 * s);
  dst[o + 1] = f2bf(x1 * s + x2 * c);
}

// ---------- flash attention ----------
// grid: (T/128, B*H). block = 256 (4 waves), wave w owns q rows [qb+w*32, +32)
__global__ __launch_bounds__(256) void attn_kernel(const u16* __restrict__ Q,
                                                   const u16* __restrict__ K,
                                                   const u16* __restrict__ V,
                                                   u16* __restrict__ O) {
  __shared__ char smem[49152];
  const int t = threadIdx.x, w = t >> 6, l = t & 63;
  const int lr = l & 15, lk8 = (l >> 4) * 8, lg4 = (l >> 4) * 4;
  const int qb = blockIdx.x * 128;
  const int b = blockIdx.y >> 4, h = blockIdx.y & 15;
  const size_t rs = 3072;
  const u16* Qg = Q + ((size_t)(b * 1024 + qb)) * rs + h * 192;
  const u16* Kg = K + ((size_t)b * 1024) * rs + h * 192;
  const u16* Vg = V + ((size_t)b * 1024) * rs + h * 192;

  // stage Q tile 128x192 bf16 (48KB), then pull frags to regs
  u16* qs = (u16*)smem;
#pragma unroll
  for (int i = 0; i < 12; ++i) {
    int lin = i * 4096 + t * 16;
    int row = lin / 384, colb = lin % 384;
    *(short8*)(smem + lin) = *(const short8*)((const char*)(Qg + (size_t)row * rs) + colb);
  }
  __syncthreads();
  short8 qf[2][6];
#pragma unroll
  for (int mf = 0; mf < 2; ++mf)
#pragma unroll
    for (int dc = 0; dc < 6; ++dc)
      qf[mf][dc] = *(const short8*)&qs[(w * 32 + mf * 16 + lr) * 192 + dc * 32 + lk8];
  __syncthreads();

  u16* ks = (u16*)smem;                  // [32][192]
  u16* vs = (u16*)(smem + 12288);        // [192][32] (transposed)
  u16* ps = (u16*)(smem + 24576 + w * 2048);  // per-wave [32][32]

  f32x4 o[2][12] = {};
  float mrow[2][4], lsum[2][4];
#pragma unroll
  for (int a = 0; a < 2; ++a)
#pragma unroll
    for (int j = 0; j < 4; ++j) { mrow[a][j] = -1e30f; lsum[a][j] = 0.f; }

  const int wq0 = qb + w * 32;
  const int nkv = (qb + 128) >> 5;
  const float scale = 0.07216878364870323f;  // 1/sqrt(192)

  for (int kt = 0; kt < nkv; ++kt) {
    const int kv0 = kt << 5;
    // stage K [32][192]
#pragma unroll
    for (int i = 0; i < 3; ++i) {
      int lin = i * 4096 + t * 16;
      int row = lin / 384, colb = lin % 384;
      *(short8*)((char*)ks + lin) =
          *(const short8*)((const char*)(Kg + (size_t)(kv0 + row) * rs) + colb);
    }
    // stage V transposed: vs[d][r]
#pragma unroll
    for (int i = 0; i < 3; ++i) {
      int c = i * 256 + t;
      int r = c / 24, dg = (c % 24) * 8;
      short8 vv = *(const short8*)(Vg + (size_t)(kv0 + r) * rs + dg);
#pragma unroll
      for (int j = 0; j < 8; ++j) vs[(dg + j) * 32 + r] = (u16)vv[j];
    }
    __syncthreads();

    if (kv0 <= wq0 + 31) {
      // S = Q K^T  (S[q][k], 2x2 frags)
      f32x4 s[2][2] = {};
#pragma unroll
      for (int dc = 0; dc < 6; ++dc) {
        short8 kf0 = *(const short8*)&ks[(lr) * 192 + dc * 32 + lk8];
        short8 kf1 = *(const short8*)&ks[(16 + lr) * 192 + dc * 32 + lk8];
        s[0][0] = mfma16(qf[0][dc], kf0, s[0][0]);
        s[0][1] = mfma16(qf[0][dc], kf1, s[0][1]);
        s[1][0] = mfma16(qf[1][dc], kf0, s[1][0]);
        s[1][1] = mfma16(qf[1][dc], kf1, s[1][1]);
      }
      // online softmax
#pragma unroll
      for (int mf = 0; mf < 2; ++mf)
#pragma unroll
        for (int j = 0; j < 4; ++j) {
          int q = wq0 + mf * 16 + lg4 + j;
          float s0 = s[mf][0][j] * scale;
          float s1 = s[mf][1][j] * scale;
          if (kv0 + lr > q) s0 = -1e30f;
          if (kv0 + 16 + lr > q) s1 = -1e30f;
          float mt = fmaxf(s0, s1);
#pragma unroll
          for (int off = 1; off < 16; off <<= 1) mt = fmaxf(mt, __shfl_xor(mt, off));
          float mnew = fmaxf(mrow[mf][j], mt);
          float corr = __expf(mrow[mf][j] - mnew);
          float p0 = __expf(s0 - mnew);
          float p1 = __expf(s1 - mnew);
          float lt = p0 + p1;
#pragma unroll
          for (int off = 1; off < 16; off <<= 1) lt += __shfl_xor(lt, off);
          lsum[mf][j] = lsum[mf][j] * corr + lt;
          mrow[mf][j] = mnew;
#pragma unroll
          for (int nf = 0; nf < 12; ++nf) o[mf][nf][j] *= corr;
          int rw = mf * 16 + lg4 + j;
          ps[rw * 32 + lr] = f2bf(p0);
          ps[rw * 32 + 16 + lr] = f2bf(p1);
        }
      // P writes -> reads within this wave only
      asm volatile("s_waitcnt lgkmcnt(0)" ::: "memory");
      __builtin_amdgcn_sched_barrier(0);
      short8 pa0 = *(const short8*)&ps[lr * 32 + lk8];
      short8 pa1 = *(const short8*)&ps[(16 + lr) * 32 + lk8];
#pragma unroll
      for (int nf = 0; nf < 12; ++nf) {
        short8 vf = *(const short8*)&vs[(nf * 16 + lr) * 32 + lk8];
        o[0][nf] = mfma16(pa0, vf, o[0][nf]);
        o[1][nf] = mfma16(pa1, vf, o[1][nf]);
      }
    }
    __syncthreads();
  }

#pragma unroll
  for (int mf = 0; mf < 2; ++mf)
#pragma unroll
    for (int j = 0; j < 4; ++j) {
      float inv = 1.0f / lsum[mf][j];
      size_t rowg = (size_t)(b * 1024 + wq0 + mf * 16 + lg4 + j);
#pragma unroll
      for (int nf = 0; nf < 12; ++nf)
        O[rowg * rs + h * 192 + nf * 16 + lr] = f2bf(o[mf][nf][j] * inv);
    }
}

// ---------- launch ----------
extern "C" void kernel_launch(void* const* d_in, const int* in_sizes, int n_in,
                              void* d_out, int out_size, void* d_ws, size_t ws_size,
                              hipStream_t stream) {
  const float* x   = (const float*)d_in[0];
  const float* wqd = (const float*)d_in[1];
  const float* wqn = (const float*)d_in[2];
  const float* wqr = (const float*)d_in[3];
  const float* wkd = (const float*)d_in[4];
  const float* wvu = (const float*)d_in[5];
  const float* wkn = (const float*)d_in[6];
  const float* wkr = (const float*)d_in[7];
  const float* wo  = (const float*)d_in[8];

  char* ws = (char*)d_ws;
  size_t off = 0;
  auto alloc = [&](size_t bytes) {
    char* p = ws + off;
    off += (bytes + 255) & ~(size_t)255;
    return p;
  };
  u16* xb   = (u16*)alloc(8388608ull * 2);       // x bf16
  u16* W1t  = (u16*)alloc(2048ull * 2048 * 2);   // [wq_down|wkv_down]^T
  u16* Wqnt = (u16*)alloc(2048ull * 1536 * 2);
  u16* Wqrt = (u16*)alloc(1024ull * 1536 * 2);
  u16* Wvt  = (u16*)alloc(3072ull * 512 * 2);
  u16* Wknt = (u16*)alloc(2048ull * 512 * 2);
  u16* Wkrt = (u16*)alloc(1024ull * 512 * 2);
  u16* Wot  = (u16*)alloc(2048ull * 3072 * 2);
  u16* lat  = (u16*)alloc(4096ull * 2048 * 2);   // [q_latent | kv_latent]
  u16* Qb   = (u16*)alloc(4096ull * 3072 * 2);
  u16* Kb   = (u16*)alloc(4096ull * 3072 * 2);
  u16* Vb   = (u16*)alloc(4096ull * 3072 * 2);
  u16* AO   = (u16*)alloc(4096ull * 3072 * 2);
  u16* qrt  = (u16*)alloc(4096ull * 1024 * 2);
  u16* krt  = (u16*)alloc(4096ull * 1024 * 2);

  castk<<<8192, 256, 0, stream>>>(x, xb, 2097152);

  tcast<<<dim3(32, 24), 256, 0, stream>>>(wqd, W1t, 2048, 1536);
  tcast<<<dim3(32, 8),  256, 0, stream>>>(wkd, W1t + 1536ull * 2048, 2048, 512);
  tcast<<<dim3(24, 32), 256, 0, stream>>>(wqn, Wqnt, 1536, 2048);
  tcast<<<dim3(24, 16), 256, 0, stream>>>(wqr, Wqrt, 1536, 1024);
  tcast<<<dim3(8, 48),  256, 0, stream>>>(wvu, Wvt, 512, 3072);
  tcast<<<dim3(8, 32),  256, 0, stream>>>(wkn, Wknt, 512, 2048);
  tcast<<<dim3(8, 16),  256, 0, stream>>>(wkr, Wkrt, 512, 1024);
  tcast<<<dim3(48, 32), 256, 0, stream>>>(wo, Wot, 3072, 2048);

  // latent = x @ [wq_down|wkv_down]
  gemm_bt<0><<<dim3(32, 16), 256, 0, stream>>>(xb, 2048, W1t, 2048, lat, 2048, 2048);
  // q_c -> Q (nope cols), q_r -> tmp
  gemm_bt<1><<<dim3(32, 16), 256, 0, stream>>>(lat, 2048, Wqnt, 1536, Qb, 3072, 1536);
  gemm_bt<0><<<dim3(32, 8),  256, 0, stream>>>(lat, 2048, Wqrt, 1536, qrt, 1024, 1536);
  // v, k_c, k_r from kv_latent (cols 1536..2047 of lat)
  gemm_bt<0><<<dim3(32, 24), 256, 0, stream>>>(lat + 1536, 2048, Wvt, 512, Vb, 3072, 512);
  gemm_bt<1><<<dim3(32, 16), 256, 0, stream>>>(lat + 1536, 2048, Wknt, 512, Kb, 3072, 512);
  gemm_bt<0><<<dim3(32, 8),  256, 0, stream>>>(lat + 1536, 2048, Wkrt, 512, krt, 1024, 512);

  rope_k<<<8192, 256, 0, stream>>>(qrt, Qb);
  rope_k<<<8192, 256, 0, stream>>>(krt, Kb);

  attn_kernel<<<dim3(8, 64), 256, 0, stream>>>(Qb, Kb, Vb, AO);

  // out = AO @ wo  (fp32 out)
  gemm_bt<2><<<dim3(32, 16), 256, 0, stream>>>(AO, 3072, Wot, 3072, d_out, 2048, 3072);
}

// Round 2
// 450.943 us; speedup vs baseline: 1.5139x; 1.5139x over previous
//
#include <hip/hip_runtime.h>

// ---------- types ----------
typedef unsigned short u16;
typedef __bf16  bf16x8 __attribute__((ext_vector_type(8)));
typedef short   short8 __attribute__((ext_vector_type(8)));
typedef float   f32x4  __attribute__((ext_vector_type(4)));
typedef u16     u16x4  __attribute__((ext_vector_type(4)));

__device__ __forceinline__ u16 f2bf(float f) {
  unsigned b = __builtin_bit_cast(unsigned, f);
  b += 0x7fffu + ((b >> 16) & 1u);          // round-to-nearest-even
  return (u16)(b >> 16);
}
__device__ __forceinline__ float bf2f(u16 u) {
  return __builtin_bit_cast(float, (unsigned)u << 16);
}
__device__ __forceinline__ f32x4 mfma16(short8 a, short8 b, f32x4 c) {
  return __builtin_amdgcn_mfma_f32_16x16x32_bf16(
      __builtin_bit_cast(bf16x8, a), __builtin_bit_cast(bf16x8, b), c, 0, 0, 0);
}
__device__ __forceinline__ void gload_lds16(const void* g, void* l) {
  __builtin_amdgcn_global_load_lds(
      (const __attribute__((address_space(1))) void*)g,
      (__attribute__((address_space(3))) void*)l, 16, 0, 0);
}

// ---------- cast x -> bf16 ----------
__global__ __launch_bounds__(256) void castk(const float* __restrict__ in,
                                             u16* __restrict__ out, int n4) {
  int i = blockIdx.x * 256 + threadIdx.x;
  if (i >= n4) return;
  float4 v = ((const float4*)in)[i];
  u16x4 o;
  o[0] = f2bf(v.x); o[1] = f2bf(v.y); o[2] = f2bf(v.z); o[3] = f2bf(v.w);
  *(u16x4*)&out[i * 4] = o;
}

// ---------- transpose-cast weight: W[K][N] f32 -> Wt[N][K] bf16 ----------
__global__ __launch_bounds__(256) void tcast(const float* __restrict__ W,
                                             u16* __restrict__ Wt, int K, int N) {
  __shared__ float tile[64][65];
  const int k0 = blockIdx.x * 64, n0 = blockIdx.y * 64;
  const int tc = threadIdx.x & 63, tr = threadIdx.x >> 6;
#pragma unroll
  for (int r = tr; r < 64; r += 4)
    tile[r][tc] = W[(size_t)(k0 + r) * N + n0 + tc];
  __syncthreads();
#pragma unroll
  for (int r = tr; r < 64; r += 4)
    Wt[(size_t)(n0 + r) * K + k0 + tc] = f2bf(tile[tc][r]);
}

// ---------- GEMM: C[M][N] = A[M][K] * Bt[N][K]^T  (bf16 in, fp32 acc) ----------
template <int EPI>
__global__ __launch_bounds__(256) void gemm_bt(const u16* __restrict__ A, int lda,
                                               const u16* __restrict__ Bt, int ldb,
                                               void* __restrict__ Cout, int ldc,
                                               int K) {
  __shared__ u16 As[128 * 32];
  __shared__ u16 Bs[128 * 32];
  const int t = threadIdx.x, w = t >> 6, l = t & 63;
  const int lr = l & 15, lk8 = (l >> 4) * 8, lg4 = (l >> 4) * 4;
  const int m0 = blockIdx.x * 128, n0 = blockIdx.y * 128;
  const int wr = (w >> 1) * 64, wc = (w & 1) * 64;

  f32x4 acc[4][4] = {};

  for (int k0 = 0; k0 < K; k0 += 32) {
#pragma unroll
    for (int i = 0; i < 2; ++i) {
      int lb = i * 4096 + t * 16;
      int row = lb >> 6;
      int col = (lb & 63) >> 1;
      gload_lds16(A + (size_t)(m0 + row) * lda + k0 + col,
                  (char*)As + i * 4096 + w * 1024);
      gload_lds16(Bt + (size_t)(n0 + row) * ldb + k0 + col,
                  (char*)Bs + i * 4096 + w * 1024);
    }
    __syncthreads();
    short8 af[4], bf[4];
#pragma unroll
    for (int m = 0; m < 4; ++m)
      af[m] = *(const short8*)&As[(wr + m * 16 + lr) * 32 + lk8];
#pragma unroll
    for (int n = 0; n < 4; ++n)
      bf[n] = *(const short8*)&Bs[(wc + n * 16 + lr) * 32 + lk8];
#pragma unroll
    for (int m = 0; m < 4; ++m)
#pragma unroll
      for (int n = 0; n < 4; ++n)
        acc[m][n] = mfma16(af[m], bf[n], acc[m][n]);
    __syncthreads();
  }

#pragma unroll
  for (int m = 0; m < 4; ++m)
#pragma unroll
    for (int n = 0; n < 4; ++n)
#pragma unroll
      for (int j = 0; j < 4; ++j) {
        int r = m0 + wr + m * 16 + lg4 + j;
        int c = n0 + wc + n * 16 + lr;
        float v = acc[m][n][j];
        if (EPI == 0) {
          ((u16*)Cout)[(size_t)r * ldc + c] = f2bf(v);
        } else if (EPI == 1) {
          int cc = (c >> 7) * 192 + (c & 127);
          ((u16*)Cout)[(size_t)r * ldc + cc] = f2bf(v);
        } else {
          ((float*)Cout)[(size_t)r * ldc + c] = v;
        }
      }
}

// ---------- RoPE ----------
__global__ __launch_bounds__(256) void rope_k(const u16* __restrict__ src,
                                              u16* __restrict__ dst) {
  int idx = blockIdx.x * 256 + threadIdx.x;
  int row = idx >> 9;
  int rem = idx & 511;
  int h = rem >> 5, i = rem & 31;
  int tpos = row & 1023;
  float inv = powf(10000.0f, -(float)i * (1.0f / 32.0f));
  float f = (float)tpos * inv;
  float s, c;
  sincosf(f, &s, &c);
  float x1 = bf2f(src[(size_t)row * 1024 + h * 64 + 2 * i]);
  float x2 = bf2f(src[(size_t)row * 1024 + h * 64 + 2 * i + 1]);
  size_t o = (size_t)row * 3072 + h * 192 + 128 + 2 * i;
  dst[o]     = f2bf(x1 * c - x2 * s);
  dst[o + 1] = f2bf(x1 * s + x2 * c);
}

// ---------- flash attention, swapped-QK^T / swizzled-LDS (m214-style) ----------
// grid: (T/128, B*H). block = 256 (4 waves); wave w owns q rows [qb+w*32, +32).
// KVBLK=64. LDS: K swz [64][192] 24KB | V^T swz [192][64] 24KB | P per-wave 4KB.
__global__ __launch_bounds__(256, 2) void attn_kernel(const u16* __restrict__ Q,
                                                      const u16* __restrict__ K,
                                                      const u16* __restrict__ V,
                                                      u16* __restrict__ O) {
  __shared__ char smem[65536];
  const int t = threadIdx.x, w = t >> 6, l = t & 63;
  const int lr = l & 15, hi = l >> 4;
  const int qb = blockIdx.x * 128;
  const int b = blockIdx.y >> 4, h = blockIdx.y & 15;
  const int wq0 = qb + w * 32;
  const size_t rs = 3072;
  const u16* Qg = Q + ((size_t)(b * 1024 + qb)) * rs + h * 192;
  const char* Kg = (const char*)(K + ((size_t)b * 1024) * rs + h * 192);
  const u16* Vg = V + ((size_t)b * 1024) * rs + h * 192;
  u16* Og = O + ((size_t)(b * 1024 + qb)) * rs + h * 192;

  char* ks  = smem;                     // K tile, XOR-swizzled rows
  char* vsb = smem + 24576;             // V^T tile, XOR-swizzled rows
  char* psw = smem + 49152 + w * 4096;  // per-wave P [32 q][64 k]

  const int swz = (lr & 7) << 4;

  // Q B-fragments straight from global (row = q = lane&15, d k-contiguous)
  short8 qfr[2][6];
#pragma unroll
  for (int qf = 0; qf < 2; ++qf)
#pragma unroll
    for (int dc = 0; dc < 6; ++dc)
      qfr[qf][dc] = *(const short8*)(Qg + (size_t)(w * 32 + qf * 16 + lr) * rs + dc * 32 + hi * 8);

  // K staging: linear LDS dest, pre-swizzled global source (rule 21 / m173)
  const char* kptr[6];
  char* kdst[6];
#pragma unroll
  for (int i = 0; i < 6; ++i) {
    int lin = (i * 4 + w) * 1024 + l * 16;
    int row = lin / 384;
    int col = lin % 384;
    kptr[i] = Kg + (size_t)row * 6144 + (col ^ ((row & 7) << 4));
    kdst[i] = ks + (i * 4 + w) * 1024;
  }
  // V staging: lane l loads row kv0+l, d-group (i*4+w)*8
  const u16* vptr = Vg + (size_t)l * rs + w * 8;

  f32x4 o[12][2] = {};
  float m[2] = {-1e30f, -1e30f}, ls[2] = {0.f, 0.f};
  const float scale = 0.07216878364870323f;  // 1/sqrt(192)
  const int nkv = (qb >> 6) + 2;

  for (int kt = 0; kt < nkv; ++kt) {
    const int kv0 = kt << 6;
    // ---- stage K (async DMA) ----
#pragma unroll
    for (int i = 0; i < 6; ++i) {
      gload_lds16(kptr[i], kdst[i]);
      kptr[i] += 393216;  // 64 rows * 6144 B
    }
    // ---- stage V^T (reg transpose, swizzled, conflict-free 2B writes) ----
#pragma unroll
    for (int i = 0; i < 6; ++i) {
      short8 vv = *(const short8*)(vptr + i * 32);
      char* vb = vsb + (i * 4 + w) * 1024;  // d = (i*4+w)*8 + jj, 128B/row
#pragma unroll
      for (int jj = 0; jj < 8; ++jj)
        *(u16*)(vb + jj * 128 + ((2 * l) ^ (jj << 4))) = (u16)vv[jj];
    }
    vptr += 196608;  // 64 * 3072 elements
    __syncthreads();

    if (kv0 <= wq0) {
      // ---- S^T = K Q^T : lane holds S^T[k = kv0+kf*16+hi*4+j][q = wq0+qf*16+lr]
      f32x4 st[4][2] = {};
#pragma unroll
      for (int dc = 0; dc < 6; ++dc) {
        const int kin = (dc * 64 + hi * 16) ^ swz;
#pragma unroll
        for (int kf = 0; kf < 4; ++kf) {
          short8 ka = *(const short8*)(ks + (kf * 16 + lr) * 384 + kin);
          st[kf][0] = mfma16(ka, qfr[0][dc], st[kf][0]);
          st[kf][1] = mfma16(ka, qfr[1][dc], st[kf][1]);
        }
      }

      // ---- online softmax, lane-local + 2 shfls ----
      const bool needmask = (kv0 + 63 > wq0);
      float mt[2];
#pragma unroll
      for (int qf = 0; qf < 2; ++qf) {
        const int q = wq0 + qf * 16 + lr;
        float mx = -1e30f;
#pragma unroll
        for (int kf = 0; kf < 4; ++kf)
#pragma unroll
          for (int j = 0; j < 4; ++j) {
            float s = st[kf][qf][j] * scale;
            if (needmask && (kv0 + kf * 16 + hi * 4 + j > q)) s = -1e30f;
            st[kf][qf][j] = s;
            mx = fmaxf(mx, s);
          }
        mx = fmaxf(mx, __shfl_xor(mx, 16));
        mx = fmaxf(mx, __shfl_xor(mx, 32));
        mt[qf] = mx;
      }
      // defer-max (T13): skip rescale when tile max within threshold
      const bool skip = __all((mt[0] <= m[0] + 8.0f) & (mt[1] <= m[1] + 8.0f));
      if (!skip) {
#pragma unroll
        for (int qf = 0; qf < 2; ++qf) {
          float mn = fmaxf(m[qf], mt[qf]);
          float corr = __expf(m[qf] - mn);
          m[qf] = mn;
          ls[qf] *= corr;
#pragma unroll
          for (int nf = 0; nf < 12; ++nf)
#pragma unroll
            for (int j = 0; j < 4; ++j) o[nf][qf][j] *= corr;
        }
      }
      // P = exp(S - m) -> per-wave LDS (swizzled), plus row-sum
#pragma unroll
      for (int qf = 0; qf < 2; ++qf) {
        float sum = 0.f;
        char* pq = psw + (qf * 16 + lr) * 128;
#pragma unroll
        for (int kf = 0; kf < 4; ++kf)
#pragma unroll
          for (int j = 0; j < 4; ++j) {
            float p = __expf(st[kf][qf][j] - m[qf]);
            sum += p;
            int kb = 2 * (kf * 16 + hi * 4 + j);
            *(u16*)(pq + (kb ^ swz)) = f2bf(p);
          }
        sum += __shfl_xor(sum, 16);
        sum += __shfl_xor(sum, 32);
        ls[qf] += sum;
      }
      // wave-local LDS RAW fence (rule 18)
      asm volatile("s_waitcnt lgkmcnt(0)" ::: "memory");
      __builtin_amdgcn_sched_barrier(0);

      // ---- O^T += V^T P : lane holds O^T[d = nf*16+hi*4+j][q = qf*16+lr]
#pragma unroll
      for (int kc = 0; kc < 2; ++kc) {
        const int inn = (kc * 64 + hi * 16) ^ swz;
        short8 pb0 = *(const short8*)(psw + lr * 128 + inn);
        short8 pb1 = *(const short8*)(psw + (16 + lr) * 128 + inn);
#pragma unroll
        for (int nf = 0; nf < 12; ++nf) {
          short8 va = *(const short8*)(vsb + (nf * 16 + lr) * 128 + inn);
          o[nf][0] = mfma16(va, pb0, o[nf][0]);
          o[nf][1] = mfma16(va, pb1, o[nf][1]);
        }
      }
    }
    __syncthreads();
  }

  // ---- epilogue: normalize, O^T -> LDS [128][192] (swizzled), coalesced store
#pragma unroll
  for (int qf = 0; qf < 2; ++qf) {
    float inv = 1.0f / ls[qf];
    char* ob = smem + (w * 32 + qf * 16 + lr) * 384;
#pragma unroll
    for (int nf = 0; nf < 12; ++nf)
#pragma unroll
      for (int j = 0; j < 4; ++j)
        *(u16*)(ob + ((nf * 32 + hi * 8 + 2 * j) ^ swz)) = f2bf(o[nf][qf][j] * inv);
  }
  __syncthreads();
#pragma unroll
  for (int i = 0; i < 12; ++i) {
    int idx = i * 256 + t;
    int row = idx / 24;
    int c16 = idx % 24;
    short8 vv = *(const short8*)(smem + row * 384 + ((c16 * 16) ^ ((row & 7) << 4)));
    *(short8*)((char*)Og + (size_t)row * 6144 + c16 * 16) = vv;
  }
}

// ---------- launch ----------
extern "C" void kernel_launch(void* const* d_in, const int* in_sizes, int n_in,
                              void* d_out, int out_size, void* d_ws, size_t ws_size,
                              hipStream_t stream) {
  const float* x   = (const float*)d_in[0];
  const float* wqd = (const float*)d_in[1];
  const float* wqn = (const float*)d_in[2];
  const float* wqr = (const float*)d_in[3];
  const float* wkd = (const float*)d_in[4];
  const float* wvu = (const float*)d_in[5];
  const float* wkn = (const float*)d_in[6];
  const float* wkr = (const float*)d_in[7];
  const float* wo  = (const float*)d_in[8];

  char* ws = (char*)d_ws;
  size_t off = 0;
  auto alloc = [&](size_t bytes) {
    char* p = ws + off;
    off += (bytes + 255) & ~(size_t)255;
    return p;
  };
  u16* xb   = (u16*)alloc(8388608ull * 2);
  u16* W1t  = (u16*)alloc(2048ull * 2048 * 2);
  u16* Wqnt = (u16*)alloc(2048ull * 1536 * 2);
  u16* Wqrt = (u16*)alloc(1024ull * 1536 * 2);
  u16* Wvt  = (u16*)alloc(3072ull * 512 * 2);
  u16* Wknt = (u16*)alloc(2048ull * 512 * 2);
  u16* Wkrt = (u16*)alloc(1024ull * 512 * 2);
  u16* Wot  = (u16*)alloc(2048ull * 3072 * 2);
  u16* lat  = (u16*)alloc(4096ull * 2048 * 2);
  u16* Qb   = (u16*)alloc(4096ull * 3072 * 2);
  u16* Kb   = (u16*)alloc(4096ull * 3072 * 2);
  u16* Vb   = (u16*)alloc(4096ull * 3072 * 2);
  u16* AO   = (u16*)alloc(4096ull * 3072 * 2);
  u16* qrt  = (u16*)alloc(4096ull * 1024 * 2);
  u16* krt  = (u16*)alloc(4096ull * 1024 * 2);

  castk<<<8192, 256, 0, stream>>>(x, xb, 2097152);

  tcast<<<dim3(32, 24), 256, 0, stream>>>(wqd, W1t, 2048, 1536);
  tcast<<<dim3(32, 8),  256, 0, stream>>>(wkd, W1t + 1536ull * 2048, 2048, 512);
  tcast<<<dim3(24, 32), 256, 0, stream>>>(wqn, Wqnt, 1536, 2048);
  tcast<<<dim3(24, 16), 256, 0, stream>>>(wqr, Wqrt, 1536, 1024);
  tcast<<<dim3(8, 48),  256, 0, stream>>>(wvu, Wvt, 512, 3072);
  tcast<<<dim3(8, 32),  256, 0, stream>>>(wkn, Wknt, 512, 2048);
  tcast<<<dim3(8, 16),  256, 0, stream>>>(wkr, Wkrt, 512, 1024);
  tcast<<<dim3(48, 32), 256, 0, stream>>>(wo, Wot, 3072, 2048);

  gemm_bt<0><<<dim3(32, 16), 256, 0, stream>>>(xb, 2048, W1t, 2048, lat, 2048, 2048);
  gemm_bt<1><<<dim3(32, 16), 256, 0, stream>>>(lat, 2048, Wqnt, 1536, Qb, 3072, 1536);
  gemm_bt<0><<<dim3(32, 8),  256, 0, stream>>>(lat, 2048, Wqrt, 1536, qrt, 1024, 1536);
  gemm_bt<0><<<dim3(32, 24), 256, 0, stream>>>(lat + 1536, 2048, Wvt, 512, Vb, 3072, 512);
  gemm_bt<1><<<dim3(32, 16), 256, 0, stream>>>(lat + 1536, 2048, Wknt, 512, Kb, 3072, 512);
  gemm_bt<0><<<dim3(32, 8),  256, 0, stream>>>(lat + 1536, 2048, Wkrt, 512, krt, 1024, 512);

  rope_k<<<8192, 256, 0, stream>>>(qrt, Qb);
  rope_k<<<8192, 256, 0, stream>>>(krt, Kb);

  attn_kernel<<<dim3(8, 64), 256, 0, stream>>>(Qb, Kb, Vb, AO);

  gemm_bt<2><<<dim3(32, 16), 256, 0, stream>>>(AO, 3072, Wot, 3072, d_out, 2048, 3072);
}

// Round 3
// 381.239 us; speedup vs baseline: 1.7906x; 1.1828x over previous
//
#include <hip/hip_runtime.h>

// ---------- types ----------
typedef unsigned short u16;
typedef __bf16  bf16x8 __attribute__((ext_vector_type(8)));
typedef short   short8 __attribute__((ext_vector_type(8)));
typedef float   f32x4  __attribute__((ext_vector_type(4)));
typedef u16     u16x4  __attribute__((ext_vector_type(4)));

__device__ __forceinline__ u16 f2bf(float f) {
  unsigned b = __builtin_bit_cast(unsigned, f);
  b += 0x7fffu + ((b >> 16) & 1u);          // round-to-nearest-even
  return (u16)(b >> 16);
}
__device__ __forceinline__ float bf2f(u16 u) {
  return __builtin_bit_cast(float, (unsigned)u << 16);
}
__device__ __forceinline__ f32x4 mfma16(short8 a, short8 b, f32x4 c) {
  return __builtin_amdgcn_mfma_f32_16x16x32_bf16(
      __builtin_bit_cast(bf16x8, a), __builtin_bit_cast(bf16x8, b), c, 0, 0, 0);
}
__device__ __forceinline__ void gload_lds16(const void* g, void* l) {
  __builtin_amdgcn_global_load_lds(
      (const __attribute__((address_space(1))) void*)g,
      (__attribute__((address_space(3))) void*)l, 16, 0, 0);
}

// ---------- cast x -> bf16 ----------
__global__ __launch_bounds__(256) void castk(const float* __restrict__ in,
                                             u16* __restrict__ out, int n4) {
  int i = blockIdx.x * 256 + threadIdx.x;
  if (i >= n4) return;
  float4 v = ((const float4*)in)[i];
  u16x4 o;
  o[0] = f2bf(v.x); o[1] = f2bf(v.y); o[2] = f2bf(v.z); o[3] = f2bf(v.w);
  *(u16x4*)&out[i * 4] = o;
}

// ---------- transpose-cast weight: W[K][N] f32 -> Wt[N][K] bf16 ----------
__global__ __launch_bounds__(256) void tcast(const float* __restrict__ W,
                                             u16* __restrict__ Wt, int K, int N) {
  __shared__ float tile[64][65];
  const int k0 = blockIdx.x * 64, n0 = blockIdx.y * 64;
  const int tc = threadIdx.x & 63, tr = threadIdx.x >> 6;
#pragma unroll
  for (int r = tr; r < 64; r += 4)
    tile[r][tc] = W[(size_t)(k0 + r) * N + n0 + tc];
  __syncthreads();
#pragma unroll
  for (int r = tr; r < 64; r += 4)
    Wt[(size_t)(n0 + r) * K + k0 + tc] = f2bf(tile[tc][r]);
}

// ---------- GEMM: C[M][N] = A[M][K] * Bt[N][K]^T  (bf16 in, fp32 acc) ----------
// EPI 0: bf16 store to out0 (ldc)
// EPI 1: two-range: c<2048 -> out0 col (c>>7)*192+(c&127), ldc; c>=2048 -> out1 col c-2048, ld 1024
// EPI 2: fp32 store to out0 (ldc)
// EPI 3: V^T store: out0[b][h][d][t] = [4][16][192][1024], via padded-LDS transpose
template <int EPI>
__global__ __launch_bounds__(256) void gemm_bt(const u16* __restrict__ A, int lda,
                                               const u16* __restrict__ Bt, int ldb,
                                               void* __restrict__ out0,
                                               void* __restrict__ out1, int ldc,
                                               int K) {
  __shared__ u16 As[128 * 32];
  __shared__ u16 Bs[128 * 32];
  __shared__ u16 epi[EPI == 3 ? 128 * 136 : 1];
  const int t = threadIdx.x, w = t >> 6, l = t & 63;
  const int lr = l & 15, lk8 = (l >> 4) * 8, lg4 = (l >> 4) * 4;
  const int m0 = blockIdx.x * 128, n0 = blockIdx.y * 128;
  const int wr = (w >> 1) * 64, wc = (w & 1) * 64;

  f32x4 acc[4][4] = {};

  for (int k0 = 0; k0 < K; k0 += 32) {
#pragma unroll
    for (int i = 0; i < 2; ++i) {
      int lb = i * 4096 + t * 16;
      int row = lb >> 6;
      int col = (lb & 63) >> 1;
      gload_lds16(A + (size_t)(m0 + row) * lda + k0 + col,
                  (char*)As + i * 4096 + w * 1024);
      gload_lds16(Bt + (size_t)(n0 + row) * ldb + k0 + col,
                  (char*)Bs + i * 4096 + w * 1024);
    }
    __syncthreads();
    short8 af[4], bf[4];
#pragma unroll
    for (int m = 0; m < 4; ++m)
      af[m] = *(const short8*)&As[(wr + m * 16 + lr) * 32 + lk8];
#pragma unroll
    for (int n = 0; n < 4; ++n)
      bf[n] = *(const short8*)&Bs[(wc + n * 16 + lr) * 32 + lk8];
#pragma unroll
    for (int m = 0; m < 4; ++m)
#pragma unroll
      for (int n = 0; n < 4; ++n)
        acc[m][n] = mfma16(af[m], bf[n], acc[m][n]);
    __syncthreads();
  }

  if constexpr (EPI == 3) {
    // transpose acc through padded LDS, store V^T coalesced
#pragma unroll
    for (int m = 0; m < 4; ++m)
#pragma unroll
      for (int n = 0; n < 4; ++n)
#pragma unroll
        for (int j = 0; j < 4; ++j)
          epi[(wc + n * 16 + lr) * 136 + (wr + m * 16 + lg4 + j)] = f2bf(acc[m][n][j]);
    __syncthreads();
    const int b = m0 >> 10, tloc = m0 & 1023;
#pragma unroll
    for (int i = 0; i < 8; ++i) {
      int idx = i * 256 + t;
      int row = idx >> 4, c16 = idx & 15;
      int cg = n0 + row;
      int h = (unsigned)cg / 192u, d = cg - h * 192;
      short8 vv = *(const short8*)&epi[row * 136 + c16 * 8];
      *(short8*)((u16*)out0 + ((size_t)(b * 16 + h) * 192 + d) * 1024 + tloc + c16 * 8) = vv;
    }
  } else {
#pragma unroll
    for (int m = 0; m < 4; ++m)
#pragma unroll
      for (int n = 0; n < 4; ++n)
#pragma unroll
        for (int j = 0; j < 4; ++j) {
          int r = m0 + wr + m * 16 + lg4 + j;
          int c = n0 + wc + n * 16 + lr;
          float v = acc[m][n][j];
          if (EPI == 0) {
            ((u16*)out0)[(size_t)r * ldc + c] = f2bf(v);
          } else if (EPI == 1) {
            if (c < 2048) {
              int cc = (c >> 7) * 192 + (c & 127);
              ((u16*)out0)[(size_t)r * ldc + cc] = f2bf(v);
            } else {
              ((u16*)out1)[(size_t)r * 1024 + (c - 2048)] = f2bf(v);
            }
          } else {
            ((float*)out0)[(size_t)r * ldc + c] = v;
          }
        }
  }
}

// ---------- RoPE (q and k in one launch) ----------
__global__ __launch_bounds__(256) void rope_k(const u16* __restrict__ qsrc,
                                              const u16* __restrict__ ksrc,
                                              u16* __restrict__ qdst,
                                              u16* __restrict__ kdst) {
  int idx = blockIdx.x * 256 + threadIdx.x;   // 2M pairs
  int row = idx >> 9;
  int rem = idx & 511;
  int h = rem >> 5, i = rem & 31;
  int tpos = row & 1023;
  float inv = exp2f(-(float)i * 0.4152410118609203f);  // 10000^(-i/32)
  float f = (float)tpos * inv;
  float s, c;
  sincosf(f, &s, &c);
  size_t si = (size_t)row * 1024 + h * 64 + 2 * i;
  size_t o = (size_t)row * 3072 + h * 192 + 128 + 2 * i;
  {
    float x1 = bf2f(qsrc[si]), x2 = bf2f(qsrc[si + 1]);
    qdst[o]     = f2bf(x1 * c - x2 * s);
    qdst[o + 1] = f2bf(x1 * s + x2 * c);
  }
  {
    float x1 = bf2f(ksrc[si]), x2 = bf2f(ksrc[si + 1]);
    kdst[o]     = f2bf(x1 * c - x2 * s);
    kdst[o + 1] = f2bf(x1 * s + x2 * c);
  }
}

// ---------- flash attention ----------
// grid: (8, B*H). block = 256 (4 waves); wave w owns q rows [qb+w*32, +32).
// KVBLK=64. LDS: K swz [64][192] 24KB | V^T swz [192][64cols] 24KB | P per-wave 4KB.
// V comes pre-transposed: Vt[b][h][d][t]. Balance swizzle pairs co-resident
// blocks so their causal work sums to a constant.
__global__ __launch_bounds__(256, 2) void attn_kernel(const u16* __restrict__ Q,
                                                      const u16* __restrict__ K,
                                                      const u16* __restrict__ Vt,
                                                      u16* __restrict__ O) {
  __shared__ char smem[65536];
  const int t = threadIdx.x, w = t >> 6, l = t & 63;
  const int lr = l & 15, hi = l >> 4;
  // work-balance swizzle: co-resident pairs (c, c+256) get qidx summing to 7
  const int tt = (blockIdx.x + (blockIdx.y >> 3)) & 7;
  const int qidx = (tt < 4) ? 2 * tt : 15 - 2 * tt;
  const int qb = qidx * 128;
  const int b = blockIdx.y >> 4, h = blockIdx.y & 15;
  const int wq0 = qb + w * 32;
  const size_t rs = 3072;
  const u16* Qg = Q + ((size_t)(b * 1024 + qb)) * rs + h * 192;
  const char* Kg = (const char*)(K + ((size_t)b * 1024) * rs + h * 192);
  const char* Vg = (const char*)(Vt + ((size_t)(b * 16 + h) * 192) * 1024);
  u16* Og = O + ((size_t)(b * 1024 + qb)) * rs + h * 192;

  char* ks  = smem;                     // K tile, XOR-swizzled rows ([64][384B])
  char* vsb = smem + 24576;             // V^T tile, XOR-swizzled rows ([192][128B])
  char* psw = smem + 49152 + w * 4096;  // per-wave P [32 q][64 k]

  const int swz = (lr & 7) << 4;

  // Q B-fragments straight from global
  short8 qfr[2][6];
#pragma unroll
  for (int qf = 0; qf < 2; ++qf)
#pragma unroll
    for (int dc = 0; dc < 6; ++dc)
      qfr[qf][dc] = *(const short8*)(Qg + (size_t)(w * 32 + qf * 16 + lr) * rs + dc * 32 + hi * 8);

  // K staging: linear LDS dest, pre-swizzled global source
  const char* kptr[6];
#pragma unroll
  for (int i = 0; i < 6; ++i) {
    int lin = (i * 4 + w) * 1024 + l * 16;
    int row = lin / 384;
    int col = lin % 384;
    kptr[i] = Kg + (size_t)row * 6144 + (col ^ ((row & 7) << 4));
  }
  // V^T staging: rows are d (2048B global stride), cols are t (2B)
  const char* vptr[6];
#pragma unroll
  for (int i = 0; i < 6; ++i) {
    int lin = (i * 4 + w) * 1024 + l * 16;
    int row = lin >> 7;          // d index
    int col = lin & 127;         // t-byte within tile
    vptr[i] = Vg + (size_t)row * 2048 + (col ^ ((row & 7) << 4));
  }

  f32x4 o[12][2] = {};
  float m[2] = {-1e30f, -1e30f}, ls[2] = {0.f, 0.f};
  const float scale = 0.07216878364870323f;  // 1/sqrt(192)
  const int nkv = 2 * qidx + 2;

  for (int kt = 0; kt < nkv; ++kt) {
    const int kv0 = kt << 6;
    // ---- stage K + V^T (async DMA) ----
#pragma unroll
    for (int i = 0; i < 6; ++i) {
      gload_lds16(kptr[i], ks + (i * 4 + w) * 1024);
      kptr[i] += 393216;  // 64 rows * 6144 B
      gload_lds16(vptr[i], vsb + (i * 4 + w) * 1024);
      vptr[i] += 128;     // 64 t * 2 B
    }
    __syncthreads();

    if (kv0 <= wq0) {
      // ---- S^T = K Q^T : lane holds S^T[k = kv0+kf*16+hi*4+j][q = wq0+qf*16+lr]
      f32x4 st[4][2] = {};
#pragma unroll
      for (int dc = 0; dc < 6; ++dc) {
        const int kin = (dc * 64 + hi * 16) ^ swz;
#pragma unroll
        for (int kf = 0; kf < 4; ++kf) {
          short8 ka = *(const short8*)(ks + (kf * 16 + lr) * 384 + kin);
          st[kf][0] = mfma16(ka, qfr[0][dc], st[kf][0]);
          st[kf][1] = mfma16(ka, qfr[1][dc], st[kf][1]);
        }
      }

      // ---- online softmax, lane-local + 2 shfls ----
      const bool needmask = (kv0 + 63 > wq0);
      float mt[2];
#pragma unroll
      for (int qf = 0; qf < 2; ++qf) {
        const int q = wq0 + qf * 16 + lr;
        float mx = -1e30f;
#pragma unroll
        for (int kf = 0; kf < 4; ++kf)
#pragma unroll
          for (int j = 0; j < 4; ++j) {
            float s = st[kf][qf][j] * scale;
            if (needmask && (kv0 + kf * 16 + hi * 4 + j > q)) s = -1e30f;
            st[kf][qf][j] = s;
            mx = fmaxf(mx, s);
          }
        mx = fmaxf(mx, __shfl_xor(mx, 16));
        mx = fmaxf(mx, __shfl_xor(mx, 32));
        mt[qf] = mx;
      }
      // defer-max (T13)
      const bool skip = __all((mt[0] <= m[0] + 8.0f) & (mt[1] <= m[1] + 8.0f));
      if (!skip) {
#pragma unroll
        for (int qf = 0; qf < 2; ++qf) {
          float mn = fmaxf(m[qf], mt[qf]);
          float corr = __expf(m[qf] - mn);
          m[qf] = mn;
          ls[qf] *= corr;
#pragma unroll
          for (int nf = 0; nf < 12; ++nf)
#pragma unroll
            for (int j = 0; j < 4; ++j) o[nf][qf][j] *= corr;
        }
      }
      // P = exp(S - m) -> per-wave LDS (swizzled), plus row-sum
#pragma unroll
      for (int qf = 0; qf < 2; ++qf) {
        float sum = 0.f;
        char* pq = psw + (qf * 16 + lr) * 128;
#pragma unroll
        for (int kf = 0; kf < 4; ++kf)
#pragma unroll
          for (int j = 0; j < 4; ++j) {
            float p = __expf(st[kf][qf][j] - m[qf]);
            sum += p;
            int kb = 2 * (kf * 16 + hi * 4 + j);
            *(u16*)(pq + (kb ^ swz)) = f2bf(p);
          }
        sum += __shfl_xor(sum, 16);
        sum += __shfl_xor(sum, 32);
        ls[qf] += sum;
      }
      // wave-local LDS RAW fence (rule 18)
      asm volatile("s_waitcnt lgkmcnt(0)" ::: "memory");
      __builtin_amdgcn_sched_barrier(0);

      // ---- O^T += V^T P : lane holds O^T[d = nf*16+hi*4+j][q = qf*16+lr]
#pragma unroll
      for (int kc = 0; kc < 2; ++kc) {
        const int inn = (kc * 64 + hi * 16) ^ swz;
        short8 pb0 = *(const short8*)(psw + lr * 128 + inn);
        short8 pb1 = *(const short8*)(psw + (16 + lr) * 128 + inn);
#pragma unroll
        for (int nf = 0; nf < 12; ++nf) {
          short8 va = *(const short8*)(vsb + (nf * 16 + lr) * 128 + inn);
          o[nf][0] = mfma16(va, pb0, o[nf][0]);
          o[nf][1] = mfma16(va, pb1, o[nf][1]);
        }
      }
    }
    __syncthreads();
  }

  // ---- epilogue: normalize, O^T -> LDS [128][192] (swizzled), coalesced store
#pragma unroll
  for (int qf = 0; qf < 2; ++qf) {
    float inv = 1.0f / ls[qf];
    char* ob = smem + (w * 32 + qf * 16 + lr) * 384;
#pragma unroll
    for (int nf = 0; nf < 12; ++nf)
#pragma unroll
      for (int j = 0; j < 4; ++j)
        *(u16*)(ob + ((nf * 32 + hi * 8 + 2 * j) ^ swz)) = f2bf(o[nf][qf][j] * inv);
  }
  __syncthreads();
#pragma unroll
  for (int i = 0; i < 12; ++i) {
    int idx = i * 256 + t;
    int row = idx / 24;
    int c16 = idx % 24;
    short8 vv = *(const short8*)(smem + row * 384 + ((c16 * 16) ^ ((row & 7) << 4)));
    *(short8*)((char*)Og + (size_t)row * 6144 + c16 * 16) = vv;
  }
}

// ---------- launch ----------
extern "C" void kernel_launch(void* const* d_in, const int* in_sizes, int n_in,
                              void* d_out, int out_size, void* d_ws, size_t ws_size,
                              hipStream_t stream) {
  const float* x   = (const float*)d_in[0];
  const float* wqd = (const float*)d_in[1];
  const float* wqn = (const float*)d_in[2];
  const float* wqr = (const float*)d_in[3];
  const float* wkd = (const float*)d_in[4];
  const float* wvu = (const float*)d_in[5];
  const float* wkn = (const float*)d_in[6];
  const float* wkr = (const float*)d_in[7];
  const float* wo  = (const float*)d_in[8];

  char* ws = (char*)d_ws;
  size_t off = 0;
  auto alloc = [&](size_t bytes) {
    char* p = ws + off;
    off += (bytes + 255) & ~(size_t)255;
    return p;
  };
  u16* xb   = (u16*)alloc(8388608ull * 2);       // x bf16
  u16* W1t  = (u16*)alloc(2048ull * 2048 * 2);   // [wq_down|wkv_down]^T
  u16* Wqt  = (u16*)alloc(3072ull * 1536 * 2);   // [wq_nope|wq_rope]^T fused
  u16* Wkt  = (u16*)alloc(3072ull * 512 * 2);    // [wk_nope|wk_rope]^T fused
  u16* Wvt  = (u16*)alloc(3072ull * 512 * 2);
  u16* Wot  = (u16*)alloc(2048ull * 3072 * 2);
  u16* lat  = (u16*)alloc(4096ull * 2048 * 2);   // [q_latent | kv_latent]
  u16* Qb   = (u16*)alloc(4096ull * 3072 * 2);
  u16* Kb   = (u16*)alloc(4096ull * 3072 * 2);
  u16* Vt   = (u16*)alloc(4096ull * 3072 * 2);   // V^T [b][h][d][t]
  u16* AO   = (u16*)alloc(4096ull * 3072 * 2);
  u16* qrt  = (u16*)alloc(4096ull * 1024 * 2);
  u16* krt  = (u16*)alloc(4096ull * 1024 * 2);

  castk<<<8192, 256, 0, stream>>>(x, xb, 2097152);

  tcast<<<dim3(32, 24), 256, 0, stream>>>(wqd, W1t, 2048, 1536);
  tcast<<<dim3(32, 8),  256, 0, stream>>>(wkd, W1t + 1536ull * 2048, 2048, 512);
  tcast<<<dim3(24, 32), 256, 0, stream>>>(wqn, Wqt, 1536, 2048);
  tcast<<<dim3(24, 16), 256, 0, stream>>>(wqr, Wqt + 2048ull * 1536, 1536, 1024);
  tcast<<<dim3(8, 32),  256, 0, stream>>>(wkn, Wkt, 512, 2048);
  tcast<<<dim3(8, 16),  256, 0, stream>>>(wkr, Wkt + 2048ull * 512, 512, 1024);
  tcast<<<dim3(8, 48),  256, 0, stream>>>(wvu, Wvt, 512, 3072);
  tcast<<<dim3(48, 32), 256, 0, stream>>>(wo, Wot, 3072, 2048);

  // latent = x @ [wq_down|wkv_down]
  gemm_bt<0><<<dim3(32, 16), 256, 0, stream>>>(xb, 2048, W1t, 2048, lat, nullptr, 2048, 2048);
  // q fused: nope -> Qb (remap), rope -> qrt
  gemm_bt<1><<<dim3(32, 24), 256, 0, stream>>>(lat, 2048, Wqt, 1536, Qb, qrt, 3072, 1536);
  // k fused: nope -> Kb (remap), rope -> krt
  gemm_bt<1><<<dim3(32, 24), 256, 0, stream>>>(lat + 1536, 2048, Wkt, 512, Kb, krt, 3072, 512);
  // v -> V^T layout
  gemm_bt<3><<<dim3(32, 24), 256, 0, stream>>>(lat + 1536, 2048, Wvt, 512, Vt, nullptr, 0, 512);

  rope_k<<<8192, 256, 0, stream>>>(qrt, krt, Qb, Kb);

  attn_kernel<<<dim3(8, 64), 256, 0, stream>>>(Qb, Kb, Vt, AO);

  // out = AO @ wo (fp32 out)
  gemm_bt<2><<<dim3(32, 16), 256, 0, stream>>>(AO, 3072, Wot, 3072, d_out, nullptr, 2048, 3072);
}

// Round 4
// 364.258 us; speedup vs baseline: 1.8741x; 1.0466x over previous
//
#include <hip/hip_runtime.h>

// ---------- types ----------
typedef unsigned short u16;
typedef __bf16  bf16x8 __attribute__((ext_vector_type(8)));
typedef short   short8 __attribute__((ext_vector_type(8)));
typedef float   f32x4  __attribute__((ext_vector_type(4)));
typedef u16     u16x4  __attribute__((ext_vector_type(4)));

__device__ __forceinline__ u16 f2bf(float f) {
  unsigned b = __builtin_bit_cast(unsigned, f);
  b += 0x7fffu + ((b >> 16) & 1u);          // round-to-nearest-even
  return (u16)(b >> 16);
}
__device__ __forceinline__ float bf2f(u16 u) {
  return __builtin_bit_cast(float, (unsigned)u << 16);
}
__device__ __forceinline__ f32x4 mfma16(short8 a, short8 b, f32x4 c) {
  return __builtin_amdgcn_mfma_f32_16x16x32_bf16(
      __builtin_bit_cast(bf16x8, a), __builtin_bit_cast(bf16x8, b), c, 0, 0, 0);
}
__device__ __forceinline__ void gload_lds16(const void* g, void* l) {
  __builtin_amdgcn_global_load_lds(
      (const __attribute__((address_space(1))) void*)g,
      (__attribute__((address_space(3))) void*)l, 16, 0, 0);
}

#define VMCNT(n) asm volatile("s_waitcnt vmcnt(" #n ")" ::: "memory")
#define MEMFENCE asm volatile("" ::: "memory")

// ---------- cast x -> bf16 ----------
__global__ __launch_bounds__(256) void castk(const float* __restrict__ in,
                                             u16* __restrict__ out, int n4) {
  int i = blockIdx.x * 256 + threadIdx.x;
  if (i >= n4) return;
  float4 v = ((const float4*)in)[i];
  u16x4 o;
  o[0] = f2bf(v.x); o[1] = f2bf(v.y); o[2] = f2bf(v.z); o[3] = f2bf(v.w);
  *(u16x4*)&out[i * 4] = o;
}

// ---------- transpose-cast weight: W[K][N] f32 -> Wt[N][K] bf16 ----------
__global__ __launch_bounds__(256) void tcast(const float* __restrict__ W,
                                             u16* __restrict__ Wt, int K, int N) {
  __shared__ float tile[64][65];
  const int k0 = blockIdx.x * 64, n0 = blockIdx.y * 64;
  const int tc = threadIdx.x & 63, tr = threadIdx.x >> 6;
#pragma unroll
  for (int r = tr; r < 64; r += 4)
    tile[r][tc] = W[(size_t)(k0 + r) * N + n0 + tc];
  __syncthreads();
#pragma unroll
  for (int r = tr; r < 64; r += 4)
    Wt[(size_t)(n0 + r) * K + k0 + tc] = f2bf(tile[tc][r]);
}

// ---------- 8-wave phased GEMM: C[M][N] = A[M][K] * Bt[N][K]^T ----------
// BM=128, BN=256, BK=32. 512 threads = 8 waves (2M x 4N), per-wave 64x64.
// 4-deep LDS ring (A 4x8KB, B 4x16KB = 96KB). Counted vmcnt(9) steady state,
// raw s_barrier (no compiler vmcnt(0) drain), setprio around MFMA cluster.
// XOR swizzle (row&3)<<4: pre-swizzled global source, same XOR on frag read.
// EPI 0: bf16 -> out0 (ldc)
// EPI 1: c<2048 -> out0 col (c>>7)*192+(c&127) (ldc); else out1 col c-2048 (ld 1024)
// EPI 2: fp32 -> out0 (ldc)
// EPI 3: fused KV (N=6144): n0<3072 -> EPI1-style to out0/out1; else V^T -> out2
template <int EPI>
__global__ __launch_bounds__(512, 2) void gemm8(const u16* __restrict__ A, int lda,
                                                const u16* __restrict__ Bt, int ldb,
                                                void* __restrict__ out0,
                                                void* __restrict__ out1,
                                                void* __restrict__ out2, int ldc,
                                                int K) {
  __shared__ char smem[98304];
  const int tid = threadIdx.x;
  const int w = tid >> 6, l = tid & 63;
  const int wr = w >> 2, wc = w & 3;
  const int lr = l & 15, lk8b = (l >> 4) << 4, lg4 = (l >> 4) * 4;

  // XCD-aware block swizzle (bijective: nwg % 8 == 0 for all our grids)
  const int nbx = gridDim.x;
  int id = blockIdx.y * nbx + blockIdx.x;
  int cpx = (nbx * gridDim.y) >> 3;
  int sid = (id & 7) * cpx + (id >> 3);
  const int m0 = (sid % nbx) * 128, n0 = (sid / nbx) * 256;

  // staging source pointers (per-lane, pre-swizzled within 64B row segment)
  const int arow = w * 16 + (l >> 2);
  const int acb = ((l & 3) << 4) ^ ((arow & 3) << 4);
  const u16* ag = A + (size_t)(m0 + arow) * lda + (acb >> 1);
  const int brow = w * 32 + (l >> 2);          // j=1 adds 16 rows; (row&3) unchanged
  const int bcb = ((l & 3) << 4) ^ ((brow & 3) << 4);
  const u16* bg0 = Bt + (size_t)(n0 + brow) * ldb + (bcb >> 1);
  const u16* bg1 = bg0 + (size_t)16 * ldb;

  // frag read offsets (ring base added per iteration)
  const int swzf = (lr & 3) << 4;
  int aoff[4], boff[4];
#pragma unroll
  for (int m = 0; m < 4; ++m)
    aoff[m] = (wr * 64 + m * 16 + lr) * 64 + (lk8b ^ swzf);
#pragma unroll
  for (int n = 0; n < 4; ++n)
    boff[n] = (wc * 64 + n * 16 + lr) * 64 + (lk8b ^ swzf);

  f32x4 acc[4][4] = {};

  auto STAGE = [&](int kt) {
    const int koff = kt << 5;
    char* ab = smem + ((kt & 3) << 13);
    char* bb = smem + 32768 + ((kt & 3) << 14);
    gload_lds16(ag + koff, ab + w * 1024);
    gload_lds16(bg0 + koff, bb + w * 2048);
    gload_lds16(bg1 + koff, bb + w * 2048 + 1024);
  };
  auto COMP = [&](int kt) {
    const char* ab = smem + ((kt & 3) << 13);
    const char* bb = smem + 32768 + ((kt & 3) << 14);
    short8 af[4], bf[4];
#pragma unroll
    for (int m = 0; m < 4; ++m) af[m] = *(const short8*)(ab + aoff[m]);
#pragma unroll
    for (int n = 0; n < 4; ++n) bf[n] = *(const short8*)(bb + boff[n]);
    __builtin_amdgcn_s_setprio(1);
#pragma unroll
    for (int m = 0; m < 4; ++m)
#pragma unroll
      for (int n = 0; n < 4; ++n)
        acc[m][n] = mfma16(af[m], bf[n], acc[m][n]);
    __builtin_amdgcn_s_setprio(0);
  };

  const int NT = K >> 5;
  STAGE(0); STAGE(1); STAGE(2);
  for (int kt = 0; kt < NT - 3; ++kt) {
    STAGE(kt + 3);
    VMCNT(9);
    __builtin_amdgcn_s_barrier();
    MEMFENCE;
    COMP(kt);
    MEMFENCE;
    __builtin_amdgcn_s_barrier();
  }
  VMCNT(6); __builtin_amdgcn_s_barrier(); MEMFENCE;
  COMP(NT - 3);
  MEMFENCE; __builtin_amdgcn_s_barrier();
  VMCNT(3); __builtin_amdgcn_s_barrier(); MEMFENCE;
  COMP(NT - 2);
  MEMFENCE; __builtin_amdgcn_s_barrier();
  VMCNT(0); __builtin_amdgcn_s_barrier(); MEMFENCE;
  COMP(NT - 1);
  MEMFENCE; __builtin_amdgcn_s_barrier();

  // ---------- epilogue ----------
  if (EPI == 3 && n0 >= 3072) {
    // V^T: transpose 128x256 acc tile through LDS, store Vt[b][h][d][t]
    u16* ldt = (u16*)smem;  // [256][136]
#pragma unroll
    for (int m = 0; m < 4; ++m)
#pragma unroll
      for (int n = 0; n < 4; ++n)
#pragma unroll
        for (int j = 0; j < 4; ++j)
          ldt[(wc * 64 + n * 16 + lr) * 136 + (wr * 64 + m * 16 + lg4 + j)] =
              f2bf(acc[m][n][j]);
    __syncthreads();
    const int b = m0 >> 10, tloc = m0 & 1023, n0v = n0 - 3072;
#pragma unroll
    for (int i = 0; i < 8; ++i) {
      int lin = i * 512 + tid;
      int col = lin >> 4, t16 = lin & 15;
      int cg = n0v + col;
      int h = (unsigned)cg / 192u, d = cg - h * 192;
      short8 vv = *(const short8*)&ldt[col * 136 + t16 * 8];
      *(short8*)((u16*)out2 + ((size_t)(b * 16 + h) * 192 + d) * 1024 + tloc + t16 * 8) = vv;
    }
    return;
  }
#pragma unroll
  for (int m = 0; m < 4; ++m)
#pragma unroll
    for (int n = 0; n < 4; ++n)
#pragma unroll
      for (int j = 0; j < 4; ++j) {
        int r = m0 + wr * 64 + m * 16 + lg4 + j;
        int c = n0 + wc * 64 + n * 16 + lr;
        float v = acc[m][n][j];
        if (EPI == 0) {
          ((u16*)out0)[(size_t)r * ldc + c] = f2bf(v);
        } else if (EPI == 1 || EPI == 3) {
          if (c < 2048) {
            int cc = (c >> 7) * 192 + (c & 127);
            ((u16*)out0)[(size_t)r * ldc + cc] = f2bf(v);
          } else {
            ((u16*)out1)[(size_t)r * 1024 + (c - 2048)] = f2bf(v);
          }
        } else {
          ((float*)out0)[(size_t)r * ldc + c] = v;
        }
      }
}

// ---------- RoPE (q and k in one launch) ----------
__global__ __launch_bounds__(256) void rope_k(const u16* __restrict__ qsrc,
                                              const u16* __restrict__ ksrc,
                                              u16* __restrict__ qdst,
                                              u16* __restrict__ kdst) {
  int idx = blockIdx.x * 256 + threadIdx.x;
  int row = idx >> 9;
  int rem = idx & 511;
  int h = rem >> 5, i = rem & 31;
  int tpos = row & 1023;
  float inv = exp2f(-(float)i * 0.4152410118609203f);  // 10000^(-i/32)
  float f = (float)tpos * inv;
  float s, c;
  sincosf(f, &s, &c);
  size_t si = (size_t)row * 1024 + h * 64 + 2 * i;
  size_t o = (size_t)row * 3072 + h * 192 + 128 + 2 * i;
  {
    float x1 = bf2f(qsrc[si]), x2 = bf2f(qsrc[si + 1]);
    qdst[o]     = f2bf(x1 * c - x2 * s);
    qdst[o + 1] = f2bf(x1 * s + x2 * c);
  }
  {
    float x1 = bf2f(ksrc[si]), x2 = bf2f(ksrc[si + 1]);
    kdst[o]     = f2bf(x1 * c - x2 * s);
    kdst[o + 1] = f2bf(x1 * s + x2 * c);
  }
}

// ---------- flash attention (unchanged from R3) ----------
__global__ __launch_bounds__(256, 2) void attn_kernel(const u16* __restrict__ Q,
                                                      const u16* __restrict__ K,
                                                      const u16* __restrict__ Vt,
                                                      u16* __restrict__ O) {
  __shared__ char smem[65536];
  const int t = threadIdx.x, w = t >> 6, l = t & 63;
  const int lr = l & 15, hi = l >> 4;
  const int tt = (blockIdx.x + (blockIdx.y >> 3)) & 7;
  const int qidx = (tt < 4) ? 2 * tt : 15 - 2 * tt;
  const int qb = qidx * 128;
  const int b = blockIdx.y >> 4, h = blockIdx.y & 15;
  const int wq0 = qb + w * 32;
  const size_t rs = 3072;
  const u16* Qg = Q + ((size_t)(b * 1024 + qb)) * rs + h * 192;
  const char* Kg = (const char*)(K + ((size_t)b * 1024) * rs + h * 192);
  const char* Vg = (const char*)(Vt + ((size_t)(b * 16 + h) * 192) * 1024);
  u16* Og = O + ((size_t)(b * 1024 + qb)) * rs + h * 192;

  char* ks  = smem;
  char* vsb = smem + 24576;
  char* psw = smem + 49152 + w * 4096;

  const int swz = (lr & 7) << 4;

  short8 qfr[2][6];
#pragma unroll
  for (int qf = 0; qf < 2; ++qf)
#pragma unroll
    for (int dc = 0; dc < 6; ++dc)
      qfr[qf][dc] = *(const short8*)(Qg + (size_t)(w * 32 + qf * 16 + lr) * rs + dc * 32 + hi * 8);

  const char* kptr[6];
#pragma unroll
  for (int i = 0; i < 6; ++i) {
    int lin = (i * 4 + w) * 1024 + l * 16;
    int row = lin / 384;
    int col = lin % 384;
    kptr[i] = Kg + (size_t)row * 6144 + (col ^ ((row & 7) << 4));
  }
  const char* vptr[6];
#pragma unroll
  for (int i = 0; i < 6; ++i) {
    int lin = (i * 4 + w) * 1024 + l * 16;
    int row = lin >> 7;
    int col = lin & 127;
    vptr[i] = Vg + (size_t)row * 2048 + (col ^ ((row & 7) << 4));
  }

  f32x4 o[12][2] = {};
  float m[2] = {-1e30f, -1e30f}, ls[2] = {0.f, 0.f};
  const float scale = 0.07216878364870323f;
  const int nkv = 2 * qidx + 2;

  for (int kt = 0; kt < nkv; ++kt) {
    const int kv0 = kt << 6;
#pragma unroll
    for (int i = 0; i < 6; ++i) {
      gload_lds16(kptr[i], ks + (i * 4 + w) * 1024);
      kptr[i] += 393216;
      gload_lds16(vptr[i], vsb + (i * 4 + w) * 1024);
      vptr[i] += 128;
    }
    __syncthreads();

    if (kv0 <= wq0) {
      f32x4 st[4][2] = {};
#pragma unroll
      for (int dc = 0; dc < 6; ++dc) {
        const int kin = (dc * 64 + hi * 16) ^ swz;
#pragma unroll
        for (int kf = 0; kf < 4; ++kf) {
          short8 ka = *(const short8*)(ks + (kf * 16 + lr) * 384 + kin);
          st[kf][0] = mfma16(ka, qfr[0][dc], st[kf][0]);
          st[kf][1] = mfma16(ka, qfr[1][dc], st[kf][1]);
        }
      }

      const bool needmask = (kv0 + 63 > wq0);
      float mt[2];
#pragma unroll
      for (int qf = 0; qf < 2; ++qf) {
        const int q = wq0 + qf * 16 + lr;
        float mx = -1e30f;
#pragma unroll
        for (int kf = 0; kf < 4; ++kf)
#pragma unroll
          for (int j = 0; j < 4; ++j) {
            float s = st[kf][qf][j] * scale;
            if (needmask && (kv0 + kf * 16 + hi * 4 + j > q)) s = -1e30f;
            st[kf][qf][j] = s;
            mx = fmaxf(mx, s);
          }
        mx = fmaxf(mx, __shfl_xor(mx, 16));
        mx = fmaxf(mx, __shfl_xor(mx, 32));
        mt[qf] = mx;
      }
      const bool skip = __all((mt[0] <= m[0] + 8.0f) & (mt[1] <= m[1] + 8.0f));
      if (!skip) {
#pragma unroll
        for (int qf = 0; qf < 2; ++qf) {
          float mn = fmaxf(m[qf], mt[qf]);
          float corr = __expf(m[qf] - mn);
          m[qf] = mn;
          ls[qf] *= corr;
#pragma unroll
          for (int nf = 0; nf < 12; ++nf)
#pragma unroll
            for (int j = 0; j < 4; ++j) o[nf][qf][j] *= corr;
        }
      }
#pragma unroll
      for (int qf = 0; qf < 2; ++qf) {
        float sum = 0.f;
        char* pq = psw + (qf * 16 + lr) * 128;
#pragma unroll
        for (int kf = 0; kf < 4; ++kf)
#pragma unroll
          for (int j = 0; j < 4; ++j) {
            float p = __expf(st[kf][qf][j] - m[qf]);
            sum += p;
            int kb = 2 * (kf * 16 + hi * 4 + j);
            *(u16*)(pq + (kb ^ swz)) = f2bf(p);
          }
        sum += __shfl_xor(sum, 16);
        sum += __shfl_xor(sum, 32);
        ls[qf] += sum;
      }
      asm volatile("s_waitcnt lgkmcnt(0)" ::: "memory");
      __builtin_amdgcn_sched_barrier(0);

#pragma unroll
      for (int kc = 0; kc < 2; ++kc) {
        const int inn = (kc * 64 + hi * 16) ^ swz;
        short8 pb0 = *(const short8*)(psw + lr * 128 + inn);
        short8 pb1 = *(const short8*)(psw + (16 + lr) * 128 + inn);
#pragma unroll
        for (int nf = 0; nf < 12; ++nf) {
          short8 va = *(const short8*)(vsb + (nf * 16 + lr) * 128 + inn);
          o[nf][0] = mfma16(va, pb0, o[nf][0]);
          o[nf][1] = mfma16(va, pb1, o[nf][1]);
        }
      }
    }
    __syncthreads();
  }

#pragma unroll
  for (int qf = 0; qf < 2; ++qf) {
    float inv = 1.0f / ls[qf];
    char* ob = smem + (w * 32 + qf * 16 + lr) * 384;
#pragma unroll
    for (int nf = 0; nf < 12; ++nf)
#pragma unroll
      for (int j = 0; j < 4; ++j)
        *(u16*)(ob + ((nf * 32 + hi * 8 + 2 * j) ^ swz)) = f2bf(o[nf][qf][j] * inv);
  }
  __syncthreads();
#pragma unroll
  for (int i = 0; i < 12; ++i) {
    int idx = i * 256 + t;
    int row = idx / 24;
    int c16 = idx % 24;
    short8 vv = *(const short8*)(smem + row * 384 + ((c16 * 16) ^ ((row & 7) << 4)));
    *(short8*)((char*)Og + (size_t)row * 6144 + c16 * 16) = vv;
  }
}

// ---------- launch ----------
extern "C" void kernel_launch(void* const* d_in, const int* in_sizes, int n_in,
                              void* d_out, int out_size, void* d_ws, size_t ws_size,
                              hipStream_t stream) {
  const float* x   = (const float*)d_in[0];
  const float* wqd = (const float*)d_in[1];
  const float* wqn = (const float*)d_in[2];
  const float* wqr = (const float*)d_in[3];
  const float* wkd = (const float*)d_in[4];
  const float* wvu = (const float*)d_in[5];
  const float* wkn = (const float*)d_in[6];
  const float* wkr = (const float*)d_in[7];
  const float* wo  = (const float*)d_in[8];

  char* ws = (char*)d_ws;
  size_t off = 0;
  auto alloc = [&](size_t bytes) {
    char* p = ws + off;
    off += (bytes + 255) & ~(size_t)255;
    return p;
  };
  u16* xb   = (u16*)alloc(8388608ull * 2);       // x bf16
  u16* W1t  = (u16*)alloc(2048ull * 2048 * 2);   // [wq_down|wkv_down]^T
  u16* Wqt  = (u16*)alloc(3072ull * 1536 * 2);   // [wq_nope|wq_rope]^T
  u16* Wkvt = (u16*)alloc(6144ull * 512 * 2);    // [wk_nope|wk_rope|wv_up]^T
  u16* Wot  = (u16*)alloc(2048ull * 3072 * 2);
  u16* lat  = (u16*)alloc(4096ull * 2048 * 2);   // [q_latent | kv_latent]
  u16* Qb   = (u16*)alloc(4096ull * 3072 * 2);
  u16* Kb   = (u16*)alloc(4096ull * 3072 * 2);
  u16* Vt   = (u16*)alloc(4096ull * 3072 * 2);   // V^T [b][h][d][t]
  u16* AO   = (u16*)alloc(4096ull * 3072 * 2);
  u16* qrt  = (u16*)alloc(4096ull * 1024 * 2);
  u16* krt  = (u16*)alloc(4096ull * 1024 * 2);

  castk<<<8192, 256, 0, stream>>>(x, xb, 2097152);

  tcast<<<dim3(32, 24), 256, 0, stream>>>(wqd, W1t, 2048, 1536);
  tcast<<<dim3(32, 8),  256, 0, stream>>>(wkd, W1t + 1536ull * 2048, 2048, 512);
  tcast<<<dim3(24, 32), 256, 0, stream>>>(wqn, Wqt, 1536, 2048);
  tcast<<<dim3(24, 16), 256, 0, stream>>>(wqr, Wqt + 2048ull * 1536, 1536, 1024);
  tcast<<<dim3(8, 32),  256, 0, stream>>>(wkn, Wkvt, 512, 2048);
  tcast<<<dim3(8, 16),  256, 0, stream>>>(wkr, Wkvt + 2048ull * 512, 512, 1024);
  tcast<<<dim3(8, 48),  256, 0, stream>>>(wvu, Wkvt + 3072ull * 512, 512, 3072);
  tcast<<<dim3(48, 32), 256, 0, stream>>>(wo, Wot, 3072, 2048);

  // latent = x @ [wq_down|wkv_down]   (M=4096, N=2048, K=2048)
  gemm8<0><<<dim3(32, 8), 512, 0, stream>>>(xb, 2048, W1t, 2048, lat, nullptr, nullptr, 2048, 2048);
  // q fused: nope -> Qb (remap), rope -> qrt   (N=3072, K=1536)
  gemm8<1><<<dim3(32, 12), 512, 0, stream>>>(lat, 2048, Wqt, 1536, Qb, qrt, nullptr, 3072, 1536);
  // kv fused: k_nope -> Kb, k_rope -> krt, v -> Vt   (N=6144, K=512)
  gemm8<3><<<dim3(32, 24), 512, 0, stream>>>(lat + 1536, 2048, Wkvt, 512, Kb, krt, Vt, 3072, 512);

  rope_k<<<8192, 256, 0, stream>>>(qrt, krt, Qb, Kb);

  attn_kernel<<<dim3(8, 64), 256, 0, stream>>>(Qb, Kb, Vt, AO);

  // out = AO @ wo (fp32 out)   (N=2048, K=3072)
  gemm8<2><<<dim3(32, 8), 512, 0, stream>>>(AO, 3072, Wot, 3072, d_out, nullptr, nullptr, 2048, 3072);
}